// Round 5
// baseline (843.950 us; speedup 1.0000x reference)
//
#include <hip/hip_runtime.h>
#include <math.h>

#define BB    16
#define PROBN 2048
#define POMO  256
#define ED    128
#define HN    8
#define DDIM  16
#define NEXP  8

// ws float offsets (total ~10.23M floats = ~40.9 MB)
#define WS_K     0
#define WS_V     (WS_K + BB*PROBN*ED)
#define WS_Q     (WS_V + BB*PROBN*ED)
#define WS_OUT   (WS_Q + BB*POMO*ED)
#define WS_MH    (WS_OUT + BB*POMO*ED)
#define WS_WC    (WS_MH + BB*POMO*ED)
#define WS_BC    (WS_WC + BB*ED*ED)
#define WS_GATES (WS_BC + BB*ED)

// ---------------------------------------------------------------------------
// K1: gating (top-2 softmax), gates -> ws, moe_loss -> d_out tail
// ---------------------------------------------------------------------------
__global__ __launch_bounds__(128) void k_gating(
    const float* __restrict__ mid, const float* __restrict__ w_gate,
    float* __restrict__ gates_ws, float* __restrict__ moe_out)
{
  __shared__ float lg[BB][NEXP];
  __shared__ float gt[BB][NEXP];
  int t = threadIdx.x;
  {
    int b = t >> 3, e = t & 7;
    float acc = 0.f;
    #pragma unroll 8
    for (int k = 0; k < ED; ++k) acc += mid[b*ED + k] * w_gate[k*NEXP + e];
    lg[b][e] = acc;
  }
  __syncthreads();
  if (t < BB) {
    int b = t;
    int i1 = 0; float v1 = lg[b][0];
    #pragma unroll
    for (int e = 1; e < NEXP; ++e) if (lg[b][e] > v1) { v1 = lg[b][e]; i1 = e; }
    int i2 = -1; float v2 = -3.0e38f;
    #pragma unroll
    for (int e = 0; e < NEXP; ++e) if (e != i1 && lg[b][e] > v2) { v2 = lg[b][e]; i2 = e; }
    float e2 = __expf(v2 - v1);          // <= 1
    float g1 = 1.f / (1.f + e2);
    #pragma unroll
    for (int e = 0; e < NEXP; ++e) gt[b][e] = 0.f;
    gt[b][i1] = g1;
    gt[b][i2] = e2 * g1;
  }
  __syncthreads();
  if (t < BB*NEXP) gates_ws[t] = gt[t >> 3][t & 7];
  if (t == 0) {
    float imp[NEXP], ldc[NEXP];
    #pragma unroll
    for (int e = 0; e < NEXP; ++e) { imp[e] = 0.f; ldc[e] = 0.f; }
    for (int b = 0; b < BB; ++b)
      #pragma unroll
      for (int e = 0; e < NEXP; ++e) {
        float g = gt[b][e];
        imp[e] += g;
        if (g > 0.f) ldc[e] += 1.f;
      }
    float im = 0.f, lm = 0.f;
    #pragma unroll
    for (int e = 0; e < NEXP; ++e) { im += imp[e]; lm += ldc[e]; }
    im *= 0.125f; lm *= 0.125f;
    float iv = 0.f, lv = 0.f;
    #pragma unroll
    for (int e = 0; e < NEXP; ++e) {
      float a = imp[e] - im; iv += a*a;
      float c = ldc[e] - lm; lv += c*c;
    }
    iv *= 0.125f; lv *= 0.125f;
    moe_out[0] = iv / (im*im + 1e-10f) + lv / (lm*lm + 1e-10f);
  }
}

// ---------------------------------------------------------------------------
// K2: combined expert weights per batch: WC[b] = sum_e g_e * expert_W[e]
// ---------------------------------------------------------------------------
__global__ __launch_bounds__(256) void k_experts(
    const float* __restrict__ gates, const float* __restrict__ eW,
    const float* __restrict__ eB, float* __restrict__ WC, float* __restrict__ BC)
{
  __shared__ float g[NEXP];
  int tid = threadIdx.x, b = blockIdx.x;
  if (tid < NEXP) g[tid] = gates[b*NEXP + tid];
  __syncthreads();
  for (int i = tid; i < ED*ED; i += 256) {
    float a = 0.f;
    #pragma unroll
    for (int e = 0; e < NEXP; ++e) a += g[e] * eW[e*ED*ED + i];
    WC[b*ED*ED + i] = a;
  }
  if (tid < ED) {
    float a = 0.f;
    #pragma unroll
    for (int e = 0; e < NEXP; ++e) a += g[e] * eB[e*ED + tid];
    BC[b*ED + tid] = a;
  }
}

// ---------------------------------------------------------------------------
// K3: K = nodes@Wk, V = nodes@Wv   (32768x128 @ 128x128, x2, shared A tile)
// ---------------------------------------------------------------------------
__global__ __launch_bounds__(256) void k_kv(
    const float* __restrict__ nodes, const float* __restrict__ Wk,
    const float* __restrict__ Wv, float* __restrict__ Kp, float* __restrict__ Vp)
{
  __shared__ __align__(16) float As[64*132];
  __shared__ __align__(16) float Wks[32*128];
  __shared__ __align__(16) float Wvs[32*128];
  int tid = threadIdx.x;
  int r0 = blockIdx.x * 64;
  #pragma unroll
  for (int j = 0; j < 8; ++j) {
    int idx = tid + j*256;
    int row = idx >> 5, c4 = (idx & 31) << 2;
    *(float4*)&As[row*132 + c4] = *(const float4*)&nodes[(size_t)(r0 + row)*ED + c4];
  }
  int colg = tid & 15, rowg = tid >> 4;
  int c0 = colg << 2;              // cols c0..c0+3 and c0+64..c0+67
  float accK[4][8], accV[4][8];
  #pragma unroll
  for (int i = 0; i < 4; ++i)
    #pragma unroll
    for (int j = 0; j < 8; ++j) { accK[i][j] = 0.f; accV[i][j] = 0.f; }

  for (int kk = 0; kk < 128; kk += 32) {
    __syncthreads();
    #pragma unroll
    for (int j = 0; j < 4; ++j) {
      int idx = tid + j*256;
      int row = idx >> 5, c4 = (idx & 31) << 2;
      *(float4*)&Wks[row*128 + c4] = *(const float4*)&Wk[(kk + row)*ED + c4];
      *(float4*)&Wvs[row*128 + c4] = *(const float4*)&Wv[(kk + row)*ED + c4];
    }
    __syncthreads();
    #pragma unroll 4
    for (int k = 0; k < 32; ++k) {
      float a[4];
      #pragma unroll
      for (int i = 0; i < 4; ++i) a[i] = As[(rowg*4 + i)*132 + kk + k];
      float4 wk0 = *(float4*)&Wks[k*128 + c0];
      float4 wk1 = *(float4*)&Wks[k*128 + c0 + 64];
      float4 wv0 = *(float4*)&Wvs[k*128 + c0];
      float4 wv1 = *(float4*)&Wvs[k*128 + c0 + 64];
      #pragma unroll
      for (int i = 0; i < 4; ++i) {
        accK[i][0] += a[i]*wk0.x; accK[i][1] += a[i]*wk0.y;
        accK[i][2] += a[i]*wk0.z; accK[i][3] += a[i]*wk0.w;
        accK[i][4] += a[i]*wk1.x; accK[i][5] += a[i]*wk1.y;
        accK[i][6] += a[i]*wk1.z; accK[i][7] += a[i]*wk1.w;
        accV[i][0] += a[i]*wv0.x; accV[i][1] += a[i]*wv0.y;
        accV[i][2] += a[i]*wv0.z; accV[i][3] += a[i]*wv0.w;
        accV[i][4] += a[i]*wv1.x; accV[i][5] += a[i]*wv1.y;
        accV[i][6] += a[i]*wv1.z; accV[i][7] += a[i]*wv1.w;
      }
    }
  }
  #pragma unroll
  for (int i = 0; i < 4; ++i) {
    size_t row = (size_t)(r0 + rowg*4 + i) * ED;
    *(float4*)&Kp[row + c0]      = make_float4(accK[i][0], accK[i][1], accK[i][2], accK[i][3]);
    *(float4*)&Kp[row + c0 + 64] = make_float4(accK[i][4], accK[i][5], accK[i][6], accK[i][7]);
    *(float4*)&Vp[row + c0]      = make_float4(accV[i][0], accV[i][1], accV[i][2], accV[i][3]);
    *(float4*)&Vp[row + c0 + 64] = make_float4(accV[i][4], accV[i][5], accV[i][6], accV[i][7]);
  }
}

// ---------------------------------------------------------------------------
// K4: Q = [last, load] @ Wq_last   (4096x129 @ 129x128)
// ---------------------------------------------------------------------------
__global__ __launch_bounds__(256) void k_q(
    const float* __restrict__ last, const float* __restrict__ loadv,
    const float* __restrict__ Wq, float* __restrict__ Qp)
{
  __shared__ __align__(16) float As[32*132];
  __shared__ __align__(16) float Ws[129*128];
  int tid = threadIdx.x;
  int r0 = blockIdx.x * 32;
  #pragma unroll
  for (int j = 0; j < 4; ++j) {
    int idx = tid + j*256;
    int row = idx >> 5, c4 = (idx & 31) << 2;
    *(float4*)&As[row*132 + c4] = *(const float4*)&last[(size_t)(r0 + row)*ED + c4];
  }
  if (tid < 32) As[tid*132 + 128] = loadv[r0 + tid];
  for (int idx = tid; idx < 4128; idx += 256)
    *(float4*)&Ws[idx*4] = *(const float4*)&Wq[idx*4];
  __syncthreads();

  int colg = tid & 15, rowg = tid >> 4;
  int c0 = colg << 2;
  float acc[2][8];
  #pragma unroll
  for (int i = 0; i < 2; ++i)
    #pragma unroll
    for (int j = 0; j < 8; ++j) acc[i][j] = 0.f;
  #pragma unroll 4
  for (int k = 0; k < 129; ++k) {
    float a0 = As[(rowg*2)*132 + k];
    float a1 = As[(rowg*2 + 1)*132 + k];
    float4 w0 = *(float4*)&Ws[k*128 + c0];
    float4 w1 = *(float4*)&Ws[k*128 + c0 + 64];
    acc[0][0] += a0*w0.x; acc[0][1] += a0*w0.y; acc[0][2] += a0*w0.z; acc[0][3] += a0*w0.w;
    acc[0][4] += a0*w1.x; acc[0][5] += a0*w1.y; acc[0][6] += a0*w1.z; acc[0][7] += a0*w1.w;
    acc[1][0] += a1*w0.x; acc[1][1] += a1*w0.y; acc[1][2] += a1*w0.z; acc[1][3] += a1*w0.w;
    acc[1][4] += a1*w1.x; acc[1][5] += a1*w1.y; acc[1][6] += a1*w1.z; acc[1][7] += a1*w1.w;
  }
  #pragma unroll
  for (int i = 0; i < 2; ++i) {
    size_t row = (size_t)(r0 + rowg*2 + i) * ED;
    *(float4*)&Qp[row + c0]      = make_float4(acc[i][0], acc[i][1], acc[i][2], acc[i][3]);
    *(float4*)&Qp[row + c0 + 64] = make_float4(acc[i][4], acc[i][5], acc[i][6], acc[i][7]);
  }
}

// ---------------------------------------------------------------------------
// K5 v5: flash attention = R3 structure (direct LDS staging, no reg prefetch,
// launch_bounds(256,4): VGPR<=64-70, NO SPILL — R2/R4 both died on acc spill)
// + zero-live-state VALU diet from R4:
//   q prescaled 0.25; float4 mask loads (quad key map nl=4nq+64j+c);
//   defer-max T13 (rescale only when tile max > m+8).
// Guard metric: k_attn WRITE_SIZE must stay ~2-4 MB (spill shows as ~1 GB).
// ---------------------------------------------------------------------------
__global__ __launch_bounds__(256, 4) void k_attn(
    const float* __restrict__ Kp, const float* __restrict__ Vp,
    const float* __restrict__ Qp, const float* __restrict__ mask,
    float* __restrict__ Op)
{
  __shared__ __align__(16) float kt[128*20];
  __shared__ __align__(16) float vt[128*20];
  int tid = threadIdx.x;
  int h = blockIdx.x & 7, b = blockIdx.x >> 3;
  int ph = blockIdx.y;
  int nq = tid & 15;
  int pg = tid >> 4;
  int prow0 = b*POMO + ph*32 + pg*2;
  const float* maskb = mask + (size_t)prow0 * PROBN;
  const float* Kb = Kp + (size_t)b*PROBN*ED + h*16;
  const float* Vb = Vp + (size_t)b*PROBN*ED + h*16;

  float q[2][16];
  #pragma unroll
  for (int qi = 0; qi < 2; ++qi)
    #pragma unroll
    for (int d4 = 0; d4 < 4; ++d4) {
      float4 t = *(const float4*)&Qp[(size_t)(prow0 + qi)*ED + h*16 + d4*4];
      q[qi][4*d4+0] = t.x*0.25f; q[qi][4*d4+1] = t.y*0.25f;
      q[qi][4*d4+2] = t.z*0.25f; q[qi][4*d4+3] = t.w*0.25f;
    }
  float m[2], l[2], acc[2][16];
  #pragma unroll
  for (int qi = 0; qi < 2; ++qi) {
    m[qi] = -1.0e30f; l[qi] = 0.f;
    #pragma unroll
    for (int dd = 0; dd < 16; ++dd) acc[qi][dd] = 0.f;
  }

  // staging: thread writes rows (tid>>2) and (tid>>2)+64, 16B at (tid&3)*4
  int srow0 = tid >> 2, sd4 = (tid & 3) << 2;
  int sp0 = sd4 ^ ((((srow0 >> 3) & 3)) << 2);
  int srow1 = srow0 + 64;
  int sp1 = sd4 ^ ((((srow1 >> 3) & 3)) << 2);

  for (int tile = 0; tile < 16; ++tile) {
    int t0 = tile << 7;
    if (tile > 0) __syncthreads();     // previous tile fully consumed
    // ---- stage K/V tile direct global->LDS (co-resident blocks hide wait) --
    *(float4*)&kt[srow0*20 + sp0] = *(const float4*)&Kb[(size_t)(t0 + srow0)*ED + sd4];
    *(float4*)&vt[srow0*20 + sp0] = *(const float4*)&Vb[(size_t)(t0 + srow0)*ED + sd4];
    *(float4*)&kt[srow1*20 + sp1] = *(const float4*)&Kb[(size_t)(t0 + srow1)*ED + sd4];
    *(float4*)&vt[srow1*20 + sp1] = *(const float4*)&Vb[(size_t)(t0 + srow1)*ED + sd4];
    __syncthreads();

    // ---- scores (mask preloaded as float4) ----
    float s[2][8];
    #pragma unroll
    for (int qi = 0; qi < 2; ++qi) {
      float4 mk0 = *(const float4*)&maskb[(size_t)qi*PROBN + t0 + 4*nq];
      float4 mk1 = *(const float4*)&maskb[(size_t)qi*PROBN + t0 + 4*nq + 64];
      s[qi][0] = mk0.x; s[qi][1] = mk0.y; s[qi][2] = mk0.z; s[qi][3] = mk0.w;
      s[qi][4] = mk1.x; s[qi][5] = mk1.y; s[qi][6] = mk1.z; s[qi][7] = mk1.w;
    }
    #pragma unroll
    for (int jc = 0; jc < 8; ++jc) {
      int nl = 4*nq + ((jc >> 2) << 6) + (jc & 3);
      int g = ((nl >> 3) & 3) << 2;
      float kr[16];
      #pragma unroll
      for (int D4 = 0; D4 < 4; ++D4) {
        float4 kv = *(float4*)&kt[nl*20 + ((D4 << 2) ^ g)];
        kr[4*D4+0] = kv.x; kr[4*D4+1] = kv.y; kr[4*D4+2] = kv.z; kr[4*D4+3] = kv.w;
      }
      #pragma unroll
      for (int qi = 0; qi < 2; ++qi) {
        float d = 0.f;
        #pragma unroll
        for (int dd = 0; dd < 16; ++dd) d += q[qi][dd] * kr[dd];
        s[qi][jc] += d;
      }
    }
    // ---- defer-max: rescale only when tile max exceeds m+8 (rare) ----
    #pragma unroll
    for (int qi = 0; qi < 2; ++qi) {
      float tm = s[qi][0];
      #pragma unroll
      for (int i = 1; i < 8; ++i) tm = fmaxf(tm, s[qi][i]);
      if (tm > m[qi] + 8.f) {
        float c = __expf(m[qi] - tm);
        m[qi] = tm;
        l[qi] *= c;
        #pragma unroll
        for (int dd = 0; dd < 16; ++dd) acc[qi][dd] *= c;
      }
    }
    // ---- exp + PV accumulate ----
    #pragma unroll
    for (int jc = 0; jc < 8; ++jc) {
      int nl = 4*nq + ((jc >> 2) << 6) + (jc & 3);
      int g = ((nl >> 3) & 3) << 2;
      float vr[16];
      #pragma unroll
      for (int D4 = 0; D4 < 4; ++D4) {
        float4 vv = *(float4*)&vt[nl*20 + ((D4 << 2) ^ g)];
        vr[4*D4+0] = vv.x; vr[4*D4+1] = vv.y; vr[4*D4+2] = vv.z; vr[4*D4+3] = vv.w;
      }
      #pragma unroll
      for (int qi = 0; qi < 2; ++qi) {
        float w = __expf(s[qi][jc] - m[qi]);
        l[qi] += w;
        #pragma unroll
        for (int dd = 0; dd < 16; ++dd) acc[qi][dd] += w * vr[dd];
      }
    }
  }

  // merge 16 stripes (tid bits 0..3, within wave)
  #pragma unroll
  for (int off = 1; off < 16; off <<= 1) {
    #pragma unroll
    for (int qi = 0; qi < 2; ++qi) {
      float m2 = __shfl_xor(m[qi], off);
      float l2 = __shfl_xor(l[qi], off);
      float M = fmaxf(m[qi], m2);
      float c1 = __expf(m[qi] - M), c2 = __expf(m2 - M);
      l[qi] = l[qi]*c1 + l2*c2;
      m[qi] = M;
      #pragma unroll
      for (int dd = 0; dd < 16; ++dd) {
        float a2 = __shfl_xor(acc[qi][dd], off);
        acc[qi][dd] = acc[qi][dd]*c1 + a2*c2;
      }
    }
  }
  // write: lanes nq<4, compile-time indexed via unrolled-if (rule #20)
  #pragma unroll
  for (int d4 = 0; d4 < 4; ++d4) {
    if (nq == d4) {
      #pragma unroll
      for (int qi = 0; qi < 2; ++qi) {
        float rl = 1.f / l[qi];
        *(float4*)&Op[(size_t)(prow0 + qi)*ED + h*16 + d4*4] =
          make_float4(acc[qi][4*d4+0]*rl, acc[qi][4*d4+1]*rl,
                      acc[qi][4*d4+2]*rl, acc[qi][4*d4+3]*rl);
      }
    }
  }
}

// ---------------------------------------------------------------------------
// K6: MH = OUT @ WC[b] + BC[b]   (per-batch 256x128 @ 128x128)
// ---------------------------------------------------------------------------
__global__ __launch_bounds__(256) void k_mh(
    const float* __restrict__ Op, const float* __restrict__ WC,
    const float* __restrict__ BC, float* __restrict__ MH)
{
  __shared__ __align__(16) float As[32*132];
  __shared__ __align__(16) float Ws[128*128];
  int tid = threadIdx.x;
  int b = blockIdx.x >> 3;
  int pt = blockIdx.x & 7;
  int r0 = b*POMO + pt*32;
  #pragma unroll
  for (int j = 0; j < 4; ++j) {
    int idx = tid + j*256;
    int row = idx >> 5, c4 = (idx & 31) << 2;
    *(float4*)&As[row*132 + c4] = *(const float4*)&Op[(size_t)(r0 + row)*ED + c4];
  }
  for (int idx = tid; idx < 4096; idx += 256)
    *(float4*)&Ws[idx*4] = *(const float4*)&WC[(size_t)b*ED*ED + idx*4];
  __syncthreads();

  int colg = tid & 15, rowg = tid >> 4;
  int c0 = colg << 2;
  float4 b0 = *(const float4*)&BC[b*ED + c0];
  float4 b1 = *(const float4*)&BC[b*ED + c0 + 64];
  float acc[2][8];
  #pragma unroll
  for (int i = 0; i < 2; ++i) {
    acc[i][0] = b0.x; acc[i][1] = b0.y; acc[i][2] = b0.z; acc[i][3] = b0.w;
    acc[i][4] = b1.x; acc[i][5] = b1.y; acc[i][6] = b1.z; acc[i][7] = b1.w;
  }
  #pragma unroll 4
  for (int k = 0; k < 128; ++k) {
    float a0 = As[(rowg*2)*132 + k];
    float a1 = As[(rowg*2 + 1)*132 + k];
    float4 w0 = *(float4*)&Ws[k*128 + c0];
    float4 w1 = *(float4*)&Ws[k*128 + c0 + 64];
    acc[0][0] += a0*w0.x; acc[0][1] += a0*w0.y; acc[0][2] += a0*w0.z; acc[0][3] += a0*w0.w;
    acc[0][4] += a0*w1.x; acc[0][5] += a0*w1.y; acc[0][6] += a0*w1.z; acc[0][7] += a0*w1.w;
    acc[1][0] += a1*w0.x; acc[1][1] += a1*w0.y; acc[1][2] += a1*w0.z; acc[1][3] += a1*w0.w;
    acc[1][4] += a1*w1.x; acc[1][5] += a1*w1.y; acc[1][6] += a1*w1.z; acc[1][7] += a1*w1.w;
  }
  #pragma unroll
  for (int i = 0; i < 2; ++i) {
    size_t row = (size_t)(r0 + rowg*2 + i) * ED;
    *(float4*)&MH[row + c0]      = make_float4(acc[i][0], acc[i][1], acc[i][2], acc[i][3]);
    *(float4*)&MH[row + c0 + 64] = make_float4(acc[i][4], acc[i][5], acc[i][6], acc[i][7]);
  }
}

// ---------------------------------------------------------------------------
// K7 v2: score2 = MH @ nodes^T / sqrt(E); probs = softmax(10*tanh + mask)
// phase 1: logits [8][2048] into LDS; phase 2 wave-parallel, no block barriers
// ---------------------------------------------------------------------------
__global__ __launch_bounds__(256) void k_final(
    const float* __restrict__ MH, const float* __restrict__ nodes,
    const float* __restrict__ mask, float* __restrict__ probs)
{
  __shared__ __align__(16) float lg[8*PROBN];     // 64 KB
  __shared__ __align__(16) float mh8[8*132];
  int tid = threadIdx.x;
  int b = blockIdx.x >> 5;
  int p0 = (blockIdx.x & 31) * 8;
  {
    int row = tid >> 5, c4 = (tid & 31) << 2;
    *(float4*)&mh8[row*132 + c4] = *(const float4*)&MH[(size_t)(b*POMO + p0 + row)*ED + c4];
  }
  __syncthreads();
  const float invs = 0.08838834764831845f;        // 1/sqrt(128)
  #pragma unroll
  for (int j = 0; j < 8; ++j) {
    int n = tid + (j << 8);
    const float4* nr = (const float4*)&nodes[(size_t)(b*PROBN + n)*ED];
    float a[8];
    #pragma unroll
    for (int p = 0; p < 8; ++p) a[p] = 0.f;
    float4 nv = nr[0];
    #pragma unroll 4
    for (int k4 = 0; k4 < 32; ++k4) {
      float4 cur = nv;
      if (k4 < 31) nv = nr[k4 + 1];
      #pragma unroll
      for (int p = 0; p < 8; ++p) {
        float4 mv = *(const float4*)&mh8[p*132 + (k4 << 2)];
        a[p] += mv.x*cur.x + mv.y*cur.y + mv.z*cur.z + mv.w*cur.w;
      }
    }
    #pragma unroll
    for (int p = 0; p < 8; ++p) lg[p*PROBN + n] = a[p] * invs;
  }
  __syncthreads();

  int wid = tid >> 6, lane = tid & 63;
  #pragma unroll
  for (int pp = 0; pp < 2; ++pp) {
    int p = wid*2 + pp;
    const float* mrow = mask + (size_t)(b*POMO + p0 + p) * PROBN;
    float* prow = probs + (size_t)(b*POMO + p0 + p) * PROBN;
    float z[32];
    float mx = -3.0e38f;
    #pragma unroll
    for (int i4 = 0; i4 < 8; ++i4) {
      int n = 4*lane + 256*i4;
      float4 lv = *(const float4*)&lg[p*PROBN + n];
      float4 mv = *(const float4*)&mrow[n];
      float z0 = 10.f - 20.f/(__expf(2.f*lv.x)+1.f) + mv.x;
      float z1 = 10.f - 20.f/(__expf(2.f*lv.y)+1.f) + mv.y;
      float z2 = 10.f - 20.f/(__expf(2.f*lv.z)+1.f) + mv.z;
      float z3 = 10.f - 20.f/(__expf(2.f*lv.w)+1.f) + mv.w;
      z[4*i4+0] = z0; z[4*i4+1] = z1; z[4*i4+2] = z2; z[4*i4+3] = z3;
      mx = fmaxf(fmaxf(fmaxf(mx, z0), fmaxf(z1, z2)), z3);
    }
    #pragma unroll
    for (int off = 32; off > 0; off >>= 1) mx = fmaxf(mx, __shfl_xor(mx, off));
    float sum = 0.f;
    #pragma unroll
    for (int k = 0; k < 32; ++k) { z[k] = __expf(z[k] - mx); sum += z[k]; }
    #pragma unroll
    for (int off = 32; off > 0; off >>= 1) sum += __shfl_xor(sum, off);
    float rs = 1.f / sum;
    #pragma unroll
    for (int i4 = 0; i4 < 8; ++i4) {
      int n = 4*lane + 256*i4;
      *(float4*)&prow[n] = make_float4(z[4*i4+0]*rs, z[4*i4+1]*rs,
                                       z[4*i4+2]*rs, z[4*i4+3]*rs);
    }
  }
}

// ---------------------------------------------------------------------------
extern "C" void kernel_launch(void* const* d_in, const int* in_sizes, int n_in,
                              void* d_out, int out_size, void* d_ws, size_t ws_size,
                              hipStream_t stream)
{
  const float* nodes  = (const float*)d_in[0];
  const float* last   = (const float*)d_in[1];
  const float* mid    = (const float*)d_in[2];
  const float* loadv  = (const float*)d_in[3];
  const float* mask   = (const float*)d_in[4];
  const float* Wq     = (const float*)d_in[5];
  const float* Wk     = (const float*)d_in[6];
  const float* Wv     = (const float*)d_in[7];
  const float* eW     = (const float*)d_in[8];
  const float* eB     = (const float*)d_in[9];
  const float* w_gate = (const float*)d_in[10];
  float* out = (float*)d_out;
  float* ws  = (float*)d_ws;

  k_gating<<<1, 128, 0, stream>>>(mid, w_gate, ws + WS_GATES, out + BB*POMO*PROBN);
  k_experts<<<16, 256, 0, stream>>>(ws + WS_GATES, eW, eB, ws + WS_WC, ws + WS_BC);
  k_kv<<<512, 256, 0, stream>>>(nodes, Wk, Wv, ws + WS_K, ws + WS_V);
  k_q<<<128, 256, 0, stream>>>(last, loadv, Wq, ws + WS_Q);
  k_attn<<<dim3(128, 8), 256, 0, stream>>>(ws + WS_K, ws + WS_V, ws + WS_Q, mask, ws + WS_OUT);
  k_mh<<<128, 256, 0, stream>>>(ws + WS_OUT, ws + WS_WC, ws + WS_BC, ws + WS_MH);
  k_final<<<512, 256, 0, stream>>>(ws + WS_MH, nodes, mask, out);
}

// Round 6
// 278.456 us; speedup vs baseline: 3.0308x; 3.0308x over previous
//
#include <hip/hip_runtime.h>
#include <math.h>

#define BB    16
#define PROBN 2048
#define POMO  256
#define ED    128
#define HN    8
#define DDIM  16
#define NEXP  8

// ws float offsets (total ~10.23M floats = ~40.9 MB)
#define WS_K     0
#define WS_V     (WS_K + BB*PROBN*ED)
#define WS_Q     (WS_V + BB*PROBN*ED)
#define WS_OUT   (WS_Q + BB*POMO*ED)
#define WS_MH    (WS_OUT + BB*POMO*ED)
#define WS_WC    (WS_MH + BB*POMO*ED)
#define WS_BC    (WS_WC + BB*ED*ED)
#define WS_GATES (WS_BC + BB*ED)

// ---------------------------------------------------------------------------
// K1: gating (top-2 softmax), gates -> ws, moe_loss -> d_out tail
// ---------------------------------------------------------------------------
__global__ __launch_bounds__(128) void k_gating(
    const float* __restrict__ mid, const float* __restrict__ w_gate,
    float* __restrict__ gates_ws, float* __restrict__ moe_out)
{
  __shared__ float lg[BB][NEXP];
  __shared__ float gt[BB][NEXP];
  int t = threadIdx.x;
  {
    int b = t >> 3, e = t & 7;
    float acc = 0.f;
    #pragma unroll 8
    for (int k = 0; k < ED; ++k) acc += mid[b*ED + k] * w_gate[k*NEXP + e];
    lg[b][e] = acc;
  }
  __syncthreads();
  if (t < BB) {
    int b = t;
    int i1 = 0; float v1 = lg[b][0];
    #pragma unroll
    for (int e = 1; e < NEXP; ++e) if (lg[b][e] > v1) { v1 = lg[b][e]; i1 = e; }
    int i2 = -1; float v2 = -3.0e38f;
    #pragma unroll
    for (int e = 0; e < NEXP; ++e) if (e != i1 && lg[b][e] > v2) { v2 = lg[b][e]; i2 = e; }
    float e2 = __expf(v2 - v1);          // <= 1
    float g1 = 1.f / (1.f + e2);
    #pragma unroll
    for (int e = 0; e < NEXP; ++e) gt[b][e] = 0.f;
    gt[b][i1] = g1;
    gt[b][i2] = e2 * g1;
  }
  __syncthreads();
  if (t < BB*NEXP) gates_ws[t] = gt[t >> 3][t & 7];
  if (t == 0) {
    float imp[NEXP], ldc[NEXP];
    #pragma unroll
    for (int e = 0; e < NEXP; ++e) { imp[e] = 0.f; ldc[e] = 0.f; }
    for (int b = 0; b < BB; ++b)
      #pragma unroll
      for (int e = 0; e < NEXP; ++e) {
        float g = gt[b][e];
        imp[e] += g;
        if (g > 0.f) ldc[e] += 1.f;
      }
    float im = 0.f, lm = 0.f;
    #pragma unroll
    for (int e = 0; e < NEXP; ++e) { im += imp[e]; lm += ldc[e]; }
    im *= 0.125f; lm *= 0.125f;
    float iv = 0.f, lv = 0.f;
    #pragma unroll
    for (int e = 0; e < NEXP; ++e) {
      float a = imp[e] - im; iv += a*a;
      float c = ldc[e] - lm; lv += c*c;
    }
    iv *= 0.125f; lv *= 0.125f;
    moe_out[0] = iv / (im*im + 1e-10f) + lv / (lm*lm + 1e-10f);
  }
}

// ---------------------------------------------------------------------------
// K2: combined expert weights per batch: WC[b] = sum_e g_e * expert_W[e]
// ---------------------------------------------------------------------------
__global__ __launch_bounds__(256) void k_experts(
    const float* __restrict__ gates, const float* __restrict__ eW,
    const float* __restrict__ eB, float* __restrict__ WC, float* __restrict__ BC)
{
  __shared__ float g[NEXP];
  int tid = threadIdx.x, b = blockIdx.x;
  if (tid < NEXP) g[tid] = gates[b*NEXP + tid];
  __syncthreads();
  for (int i = tid; i < ED*ED; i += 256) {
    float a = 0.f;
    #pragma unroll
    for (int e = 0; e < NEXP; ++e) a += g[e] * eW[e*ED*ED + i];
    WC[b*ED*ED + i] = a;
  }
  if (tid < ED) {
    float a = 0.f;
    #pragma unroll
    for (int e = 0; e < NEXP; ++e) a += g[e] * eB[e*ED + tid];
    BC[b*ED + tid] = a;
  }
}

// ---------------------------------------------------------------------------
// K3: K = nodes@Wk, V = nodes@Wv   (32768x128 @ 128x128, x2, shared A tile)
// ---------------------------------------------------------------------------
__global__ __launch_bounds__(256) void k_kv(
    const float* __restrict__ nodes, const float* __restrict__ Wk,
    const float* __restrict__ Wv, float* __restrict__ Kp, float* __restrict__ Vp)
{
  __shared__ __align__(16) float As[64*132];
  __shared__ __align__(16) float Wks[32*128];
  __shared__ __align__(16) float Wvs[32*128];
  int tid = threadIdx.x;
  int r0 = blockIdx.x * 64;
  #pragma unroll
  for (int j = 0; j < 8; ++j) {
    int idx = tid + j*256;
    int row = idx >> 5, c4 = (idx & 31) << 2;
    *(float4*)&As[row*132 + c4] = *(const float4*)&nodes[(size_t)(r0 + row)*ED + c4];
  }
  int colg = tid & 15, rowg = tid >> 4;
  int c0 = colg << 2;              // cols c0..c0+3 and c0+64..c0+67
  float accK[4][8], accV[4][8];
  #pragma unroll
  for (int i = 0; i < 4; ++i)
    #pragma unroll
    for (int j = 0; j < 8; ++j) { accK[i][j] = 0.f; accV[i][j] = 0.f; }

  for (int kk = 0; kk < 128; kk += 32) {
    __syncthreads();
    #pragma unroll
    for (int j = 0; j < 4; ++j) {
      int idx = tid + j*256;
      int row = idx >> 5, c4 = (idx & 31) << 2;
      *(float4*)&Wks[row*128 + c4] = *(const float4*)&Wk[(kk + row)*ED + c4];
      *(float4*)&Wvs[row*128 + c4] = *(const float4*)&Wv[(kk + row)*ED + c4];
    }
    __syncthreads();
    #pragma unroll 4
    for (int k = 0; k < 32; ++k) {
      float a[4];
      #pragma unroll
      for (int i = 0; i < 4; ++i) a[i] = As[(rowg*4 + i)*132 + kk + k];
      float4 wk0 = *(float4*)&Wks[k*128 + c0];
      float4 wk1 = *(float4*)&Wks[k*128 + c0 + 64];
      float4 wv0 = *(float4*)&Wvs[k*128 + c0];
      float4 wv1 = *(float4*)&Wvs[k*128 + c0 + 64];
      #pragma unroll
      for (int i = 0; i < 4; ++i) {
        accK[i][0] += a[i]*wk0.x; accK[i][1] += a[i]*wk0.y;
        accK[i][2] += a[i]*wk0.z; accK[i][3] += a[i]*wk0.w;
        accK[i][4] += a[i]*wk1.x; accK[i][5] += a[i]*wk1.y;
        accK[i][6] += a[i]*wk1.z; accK[i][7] += a[i]*wk1.w;
        accV[i][0] += a[i]*wv0.x; accV[i][1] += a[i]*wv0.y;
        accV[i][2] += a[i]*wv0.z; accV[i][3] += a[i]*wv0.w;
        accV[i][4] += a[i]*wv1.x; accV[i][5] += a[i]*wv1.y;
        accV[i][6] += a[i]*wv1.z; accV[i][7] += a[i]*wv1.w;
      }
    }
  }
  #pragma unroll
  for (int i = 0; i < 4; ++i) {
    size_t row = (size_t)(r0 + rowg*4 + i) * ED;
    *(float4*)&Kp[row + c0]      = make_float4(accK[i][0], accK[i][1], accK[i][2], accK[i][3]);
    *(float4*)&Kp[row + c0 + 64] = make_float4(accK[i][4], accK[i][5], accK[i][6], accK[i][7]);
    *(float4*)&Vp[row + c0]      = make_float4(accV[i][0], accV[i][1], accV[i][2], accV[i][3]);
    *(float4*)&Vp[row + c0 + 64] = make_float4(accV[i][4], accV[i][5], accV[i][6], accV[i][7]);
  }
}

// ---------------------------------------------------------------------------
// K4: Q = [last, load] @ Wq_last   (4096x129 @ 129x128)
// ---------------------------------------------------------------------------
__global__ __launch_bounds__(256) void k_q(
    const float* __restrict__ last, const float* __restrict__ loadv,
    const float* __restrict__ Wq, float* __restrict__ Qp)
{
  __shared__ __align__(16) float As[32*132];
  __shared__ __align__(16) float Ws[129*128];
  int tid = threadIdx.x;
  int r0 = blockIdx.x * 32;
  #pragma unroll
  for (int j = 0; j < 4; ++j) {
    int idx = tid + j*256;
    int row = idx >> 5, c4 = (idx & 31) << 2;
    *(float4*)&As[row*132 + c4] = *(const float4*)&last[(size_t)(r0 + row)*ED + c4];
  }
  if (tid < 32) As[tid*132 + 128] = loadv[r0 + tid];
  for (int idx = tid; idx < 4128; idx += 256)
    *(float4*)&Ws[idx*4] = *(const float4*)&Wq[idx*4];
  __syncthreads();

  int colg = tid & 15, rowg = tid >> 4;
  int c0 = colg << 2;
  float acc[2][8];
  #pragma unroll
  for (int i = 0; i < 2; ++i)
    #pragma unroll
    for (int j = 0; j < 8; ++j) acc[i][j] = 0.f;
  #pragma unroll 4
  for (int k = 0; k < 129; ++k) {
    float a0 = As[(rowg*2)*132 + k];
    float a1 = As[(rowg*2 + 1)*132 + k];
    float4 w0 = *(float4*)&Ws[k*128 + c0];
    float4 w1 = *(float4*)&Ws[k*128 + c0 + 64];
    acc[0][0] += a0*w0.x; acc[0][1] += a0*w0.y; acc[0][2] += a0*w0.z; acc[0][3] += a0*w0.w;
    acc[0][4] += a0*w1.x; acc[0][5] += a0*w1.y; acc[0][6] += a0*w1.z; acc[0][7] += a0*w1.w;
    acc[1][0] += a1*w0.x; acc[1][1] += a1*w0.y; acc[1][2] += a1*w0.z; acc[1][3] += a1*w0.w;
    acc[1][4] += a1*w1.x; acc[1][5] += a1*w1.y; acc[1][6] += a1*w1.z; acc[1][7] += a1*w1.w;
  }
  #pragma unroll
  for (int i = 0; i < 2; ++i) {
    size_t row = (size_t)(r0 + rowg*2 + i) * ED;
    *(float4*)&Qp[row + c0]      = make_float4(acc[i][0], acc[i][1], acc[i][2], acc[i][3]);
    *(float4*)&Qp[row + c0 + 64] = make_float4(acc[i][4], acc[i][5], acc[i][6], acc[i][7]);
  }
}

// ---------------------------------------------------------------------------
// K5 = R3's proven version (112 µs, VGPR 64, no scratch).
// grid (x = h + 8*b = 128, y = ph = 8), 256 thr, 32 q/block, 2 q/thread.
// nq = tid&15 owns interleaved rows {nq + 16*i}. Per-tile max + one rescale.
// DO NOT add: reg prefetch, quad-key float4 mask map, defer-max branch —
// each reintroduced GB-scale scratch traffic (R2/R4/R5 post-mortems).
// ---------------------------------------------------------------------------
__global__ __launch_bounds__(256, 4) void k_attn(
    const float* __restrict__ Kp, const float* __restrict__ Vp,
    const float* __restrict__ Qp, const float* __restrict__ mask,
    float* __restrict__ Op)
{
  __shared__ __align__(16) float kt[128*20];
  __shared__ __align__(16) float vt[128*20];
  int tid = threadIdx.x;
  int h = blockIdx.x & 7, b = blockIdx.x >> 3;
  int ph = blockIdx.y;
  int nq = tid & 15;          // 16 stripes, rows nq + 16*i
  int pg = tid >> 4;          // 16 groups x 2 queries = 32 q/block
  int prow0 = b*POMO + ph*32 + pg*2;
  const float* maskb = mask + (size_t)prow0 * PROBN;
  const float* Kb = Kp + (size_t)b*PROBN*ED + h*16;
  const float* Vb = Vp + (size_t)b*PROBN*ED + h*16;

  float q[2][16];
  #pragma unroll
  for (int qi = 0; qi < 2; ++qi)
    #pragma unroll
    for (int d4 = 0; d4 < 4; ++d4) {
      float4 t = *(const float4*)&Qp[(size_t)(prow0 + qi)*ED + h*16 + d4*4];
      q[qi][4*d4+0] = t.x; q[qi][4*d4+1] = t.y; q[qi][4*d4+2] = t.z; q[qi][4*d4+3] = t.w;
    }
  float m[2], l[2], acc[2][16];
  #pragma unroll
  for (int qi = 0; qi < 2; ++qi) {
    m[qi] = -1.0e30f; l[qi] = 0.f;
    #pragma unroll
    for (int dd = 0; dd < 16; ++dd) acc[qi][dd] = 0.f;
  }

  // staging geometry: idx = tid + j*256 -> row = idx>>2, d4 = (idx&3)<<2
  // column XOR'd with row bit3 (matches read-side sw) -> conflict-free
  int srow0 = tid >> 2, sd4 = (tid & 3) << 2;
  int sp0 = sd4 ^ (((srow0 >> 3) & 1) << 2);
  int srow1 = srow0 + 64;
  int sp1 = sd4 ^ (((srow1 >> 3) & 1) << 2);
  int sw = ((nq >> 3) & 1) << 2;

  for (int tile = 0; tile < 16; ++tile) {
    int t0 = tile << 7;
    if (tile > 0) __syncthreads();     // previous tile fully consumed
    // ---- stage K/V tile (one coalesced batch; other blocks hide the wait) --
    *(float4*)&kt[srow0*20 + sp0] = *(const float4*)&Kb[(size_t)(t0 + srow0)*ED + sd4];
    *(float4*)&vt[srow0*20 + sp0] = *(const float4*)&Vb[(size_t)(t0 + srow0)*ED + sd4];
    *(float4*)&kt[srow1*20 + sp1] = *(const float4*)&Kb[(size_t)(t0 + srow1)*ED + sd4];
    *(float4*)&vt[srow1*20 + sp1] = *(const float4*)&Vb[(size_t)(t0 + srow1)*ED + sd4];
    __syncthreads();

    // ---- scores: s[q][i] = q . K[nq+16i] * 0.25 + mask ----
    float s[2][8];
    #pragma unroll
    for (int qi = 0; qi < 2; ++qi)
      #pragma unroll
      for (int i = 0; i < 8; ++i)
        s[qi][i] = maskb[(size_t)qi*PROBN + t0 + nq + 16*i];
    #pragma unroll
    for (int i = 0; i < 8; ++i) {
      int nl = nq + 16*i;
      float kr[16];
      #pragma unroll
      for (int D4 = 0; D4 < 4; ++D4) {
        float4 kv = *(float4*)&kt[nl*20 + ((D4 << 2) ^ sw)];
        kr[4*D4+0] = kv.x; kr[4*D4+1] = kv.y; kr[4*D4+2] = kv.z; kr[4*D4+3] = kv.w;
      }
      #pragma unroll
      for (int qi = 0; qi < 2; ++qi) {
        float d = 0.f;
        #pragma unroll
        for (int dd = 0; dd < 16; ++dd) d += q[qi][dd] * kr[dd];
        s[qi][i] += d * 0.25f;
      }
    }
    // ---- per-tile max merge + single rescale ----
    #pragma unroll
    for (int qi = 0; qi < 2; ++qi) {
      float tm = s[qi][0];
      #pragma unroll
      for (int i = 1; i < 8; ++i) tm = fmaxf(tm, s[qi][i]);
      float M = fmaxf(m[qi], tm);
      float c = __expf(m[qi] - M);
      m[qi] = M;
      l[qi] *= c;
      #pragma unroll
      for (int dd = 0; dd < 16; ++dd) acc[qi][dd] *= c;
    }
    // ---- exp + PV accumulate ----
    #pragma unroll
    for (int i = 0; i < 8; ++i) {
      int nl = nq + 16*i;
      float vr[16];
      #pragma unroll
      for (int D4 = 0; D4 < 4; ++D4) {
        float4 vv = *(float4*)&vt[nl*20 + ((D4 << 2) ^ sw)];
        vr[4*D4+0] = vv.x; vr[4*D4+1] = vv.y; vr[4*D4+2] = vv.z; vr[4*D4+3] = vv.w;
      }
      #pragma unroll
      for (int qi = 0; qi < 2; ++qi) {
        float w = __expf(s[qi][i] - m[qi]);
        l[qi] += w;
        #pragma unroll
        for (int dd = 0; dd < 16; ++dd) acc[qi][dd] += w * vr[dd];
      }
    }
  }

  // merge 16 stripes (tid bits 0..3, within wave)
  #pragma unroll
  for (int off = 1; off < 16; off <<= 1) {
    #pragma unroll
    for (int qi = 0; qi < 2; ++qi) {
      float m2 = __shfl_xor(m[qi], off);
      float l2 = __shfl_xor(l[qi], off);
      float M = fmaxf(m[qi], m2);
      float c1 = __expf(m[qi] - M), c2 = __expf(m2 - M);
      l[qi] = l[qi]*c1 + l2*c2;
      m[qi] = M;
      #pragma unroll
      for (int dd = 0; dd < 16; ++dd) {
        float a2 = __shfl_xor(acc[qi][dd], off);
        acc[qi][dd] = acc[qi][dd]*c1 + a2*c2;
      }
    }
  }
  // write: lanes nq<4, compile-time indexed via unrolled-if (rule #20)
  #pragma unroll
  for (int d4 = 0; d4 < 4; ++d4) {
    if (nq == d4) {
      #pragma unroll
      for (int qi = 0; qi < 2; ++qi) {
        float rl = 1.f / l[qi];
        *(float4*)&Op[(size_t)(prow0 + qi)*ED + h*16 + d4*4] =
          make_float4(acc[qi][4*d4+0]*rl, acc[qi][4*d4+1]*rl,
                      acc[qi][4*d4+2]*rl, acc[qi][4*d4+3]*rl);
      }
    }
  }
}

// ---------------------------------------------------------------------------
// K6: MH = OUT @ WC[b] + BC[b]   (per-batch 256x128 @ 128x128)
// ---------------------------------------------------------------------------
__global__ __launch_bounds__(256) void k_mh(
    const float* __restrict__ Op, const float* __restrict__ WC,
    const float* __restrict__ BC, float* __restrict__ MH)
{
  __shared__ __align__(16) float As[32*132];
  __shared__ __align__(16) float Ws[128*128];
  int tid = threadIdx.x;
  int b = blockIdx.x >> 3;
  int pt = blockIdx.x & 7;
  int r0 = b*POMO + pt*32;
  #pragma unroll
  for (int j = 0; j < 4; ++j) {
    int idx = tid + j*256;
    int row = idx >> 5, c4 = (idx & 31) << 2;
    *(float4*)&As[row*132 + c4] = *(const float4*)&Op[(size_t)(r0 + row)*ED + c4];
  }
  for (int idx = tid; idx < 4096; idx += 256)
    *(float4*)&Ws[idx*4] = *(const float4*)&WC[(size_t)b*ED*ED + idx*4];
  __syncthreads();

  int colg = tid & 15, rowg = tid >> 4;
  int c0 = colg << 2;
  float4 b0 = *(const float4*)&BC[b*ED + c0];
  float4 b1 = *(const float4*)&BC[b*ED + c0 + 64];
  float acc[2][8];
  #pragma unroll
  for (int i = 0; i < 2; ++i) {
    acc[i][0] = b0.x; acc[i][1] = b0.y; acc[i][2] = b0.z; acc[i][3] = b0.w;
    acc[i][4] = b1.x; acc[i][5] = b1.y; acc[i][6] = b1.z; acc[i][7] = b1.w;
  }
  #pragma unroll 4
  for (int k = 0; k < 128; ++k) {
    float a0 = As[(rowg*2)*132 + k];
    float a1 = As[(rowg*2 + 1)*132 + k];
    float4 w0 = *(float4*)&Ws[k*128 + c0];
    float4 w1 = *(float4*)&Ws[k*128 + c0 + 64];
    acc[0][0] += a0*w0.x; acc[0][1] += a0*w0.y; acc[0][2] += a0*w0.z; acc[0][3] += a0*w0.w;
    acc[0][4] += a0*w1.x; acc[0][5] += a0*w1.y; acc[0][6] += a0*w1.z; acc[0][7] += a0*w1.w;
    acc[1][0] += a1*w0.x; acc[1][1] += a1*w0.y; acc[1][2] += a1*w0.z; acc[1][3] += a1*w0.w;
    acc[1][4] += a1*w1.x; acc[1][5] += a1*w1.y; acc[1][6] += a1*w1.z; acc[1][7] += a1*w1.w;
  }
  #pragma unroll
  for (int i = 0; i < 2; ++i) {
    size_t row = (size_t)(r0 + rowg*2 + i) * ED;
    *(float4*)&MH[row + c0]      = make_float4(acc[i][0], acc[i][1], acc[i][2], acc[i][3]);
    *(float4*)&MH[row + c0 + 64] = make_float4(acc[i][4], acc[i][5], acc[i][6], acc[i][7]);
  }
}

// ---------------------------------------------------------------------------
// K7 v2: score2 = MH @ nodes^T / sqrt(E); probs = softmax(10*tanh + mask)
// phase 1: logits [8][2048] into LDS; phase 2 wave-parallel, no block barriers
// ---------------------------------------------------------------------------
__global__ __launch_bounds__(256) void k_final(
    const float* __restrict__ MH, const float* __restrict__ nodes,
    const float* __restrict__ mask, float* __restrict__ probs)
{
  __shared__ __align__(16) float lg[8*PROBN];     // 64 KB
  __shared__ __align__(16) float mh8[8*132];
  int tid = threadIdx.x;
  int b = blockIdx.x >> 5;
  int p0 = (blockIdx.x & 31) * 8;
  {
    int row = tid >> 5, c4 = (tid & 31) << 2;
    *(float4*)&mh8[row*132 + c4] = *(const float4*)&MH[(size_t)(b*POMO + p0 + row)*ED + c4];
  }
  __syncthreads();
  const float invs = 0.08838834764831845f;        // 1/sqrt(128)
  #pragma unroll
  for (int j = 0; j < 8; ++j) {
    int n = tid + (j << 8);
    const float4* nr = (const float4*)&nodes[(size_t)(b*PROBN + n)*ED];
    float a[8];
    #pragma unroll
    for (int p = 0; p < 8; ++p) a[p] = 0.f;
    float4 nv = nr[0];
    #pragma unroll 4
    for (int k4 = 0; k4 < 32; ++k4) {
      float4 cur = nv;
      if (k4 < 31) nv = nr[k4 + 1];
      #pragma unroll
      for (int p = 0; p < 8; ++p) {
        float4 mv = *(const float4*)&mh8[p*132 + (k4 << 2)];
        a[p] += mv.x*cur.x + mv.y*cur.y + mv.z*cur.z + mv.w*cur.w;
      }
    }
    #pragma unroll
    for (int p = 0; p < 8; ++p) lg[p*PROBN + n] = a[p] * invs;
  }
  __syncthreads();

  int wid = tid >> 6, lane = tid & 63;
  #pragma unroll
  for (int pp = 0; pp < 2; ++pp) {
    int p = wid*2 + pp;
    const float* mrow = mask + (size_t)(b*POMO + p0 + p) * PROBN;
    float* prow = probs + (size_t)(b*POMO + p0 + p) * PROBN;
    float z[32];
    float mx = -3.0e38f;
    #pragma unroll
    for (int i4 = 0; i4 < 8; ++i4) {
      int n = 4*lane + 256*i4;
      float4 lv = *(const float4*)&lg[p*PROBN + n];
      float4 mv = *(const float4*)&mrow[n];
      float z0 = 10.f - 20.f/(__expf(2.f*lv.x)+1.f) + mv.x;
      float z1 = 10.f - 20.f/(__expf(2.f*lv.y)+1.f) + mv.y;
      float z2 = 10.f - 20.f/(__expf(2.f*lv.z)+1.f) + mv.z;
      float z3 = 10.f - 20.f/(__expf(2.f*lv.w)+1.f) + mv.w;
      z[4*i4+0] = z0; z[4*i4+1] = z1; z[4*i4+2] = z2; z[4*i4+3] = z3;
      mx = fmaxf(fmaxf(fmaxf(mx, z0), fmaxf(z1, z2)), z3);
    }
    #pragma unroll
    for (int off = 32; off > 0; off >>= 1) mx = fmaxf(mx, __shfl_xor(mx, off));
    float sum = 0.f;
    #pragma unroll
    for (int k = 0; k < 32; ++k) { z[k] = __expf(z[k] - mx); sum += z[k]; }
    #pragma unroll
    for (int off = 32; off > 0; off >>= 1) sum += __shfl_xor(sum, off);
    float rs = 1.f / sum;
    #pragma unroll
    for (int i4 = 0; i4 < 8; ++i4) {
      int n = 4*lane + 256*i4;
      *(float4*)&prow[n] = make_float4(z[4*i4+0]*rs, z[4*i4+1]*rs,
                                       z[4*i4+2]*rs, z[4*i4+3]*rs);
    }
  }
}

// ---------------------------------------------------------------------------
extern "C" void kernel_launch(void* const* d_in, const int* in_sizes, int n_in,
                              void* d_out, int out_size, void* d_ws, size_t ws_size,
                              hipStream_t stream)
{
  const float* nodes  = (const float*)d_in[0];
  const float* last   = (const float*)d_in[1];
  const float* mid    = (const float*)d_in[2];
  const float* loadv  = (const float*)d_in[3];
  const float* mask   = (const float*)d_in[4];
  const float* Wq     = (const float*)d_in[5];
  const float* Wk     = (const float*)d_in[6];
  const float* Wv     = (const float*)d_in[7];
  const float* eW     = (const float*)d_in[8];
  const float* eB     = (const float*)d_in[9];
  const float* w_gate = (const float*)d_in[10];
  float* out = (float*)d_out;
  float* ws  = (float*)d_ws;

  k_gating<<<1, 128, 0, stream>>>(mid, w_gate, ws + WS_GATES, out + BB*POMO*PROBN);
  k_experts<<<16, 256, 0, stream>>>(ws + WS_GATES, eW, eB, ws + WS_WC, ws + WS_BC);
  k_kv<<<512, 256, 0, stream>>>(nodes, Wk, Wv, ws + WS_K, ws + WS_V);
  k_q<<<128, 256, 0, stream>>>(last, loadv, Wq, ws + WS_Q);
  k_attn<<<dim3(128, 8), 256, 0, stream>>>(ws + WS_K, ws + WS_V, ws + WS_Q, mask, ws + WS_OUT);
  k_mh<<<128, 256, 0, stream>>>(ws + WS_OUT, ws + WS_WC, ws + WS_BC, ws + WS_MH);
  k_final<<<512, 256, 0, stream>>>(ws + WS_MH, nodes, mask, out);
}